// Round 5
// baseline (307.267 us; speedup 1.0000x reference)
//
#include <hip/hip_runtime.h>
#include <hip/hip_bf16.h>
#include <stdint.h>

typedef __bf16 bf16_t;
typedef __attribute__((ext_vector_type(8))) __bf16 bf16x8;
typedef __attribute__((ext_vector_type(4))) float f32x4;
typedef __attribute__((ext_vector_type(16))) float f32x16;

#define DIM_IN  4096
#define DIM_OUT 4096
#define DIM_S   1024
#define DIM_S2  2048
#define NROWS   8192   // B*T = 4*2048

typedef const __attribute__((address_space(1))) void gvoid_t;
typedef __attribute__((address_space(3))) void lvoid_t;

__device__ __forceinline__ float signf(float v) {
    return (v > 0.f) ? 1.f : ((v < 0.f) ? -1.f : 0.f);
}

// ---------------- prep kernels ----------------

__global__ void cast_x_kernel(const float* __restrict__ x, bf16_t* __restrict__ xb) {
    int idx = blockIdx.x * blockDim.x + threadIdx.x;
    const float4* p = reinterpret_cast<const float4*>(x) + (size_t)idx * 2;
    float4 a = p[0], b = p[1];
    bf16x8 o;
    o[0] = (bf16_t)a.x; o[1] = (bf16_t)a.y; o[2] = (bf16_t)a.z; o[3] = (bf16_t)a.w;
    o[4] = (bf16_t)b.x; o[5] = (bf16_t)b.y; o[6] = (bf16_t)b.z; o[7] = (bf16_t)b.w;
    reinterpret_cast<bf16x8*>(xb)[idx] = o;
}

__global__ void build_vcat_kernel(const float* __restrict__ V, const float* __restrict__ v2,
                                  const float* __restrict__ V_R, const float* __restrict__ v2_R,
                                  bf16_t* __restrict__ out) {
    int idx = blockIdx.x * blockDim.x + threadIdx.x;
    int s2 = idx >> 9;
    int i0 = (idx & 511) * 8;
    const float* src; const float* sc;
    if (s2 < DIM_S) { src = V   + (size_t)s2 * DIM_IN;           sc = v2;   }
    else            { src = V_R + (size_t)(s2 - DIM_S) * DIM_IN; sc = v2_R; }
    float4 a  = *reinterpret_cast<const float4*>(src + i0);
    float4 b  = *reinterpret_cast<const float4*>(src + i0 + 4);
    float4 sa = *reinterpret_cast<const float4*>(sc + i0);
    float4 sb = *reinterpret_cast<const float4*>(sc + i0 + 4);
    bf16x8 o;
    o[0] = (bf16_t)(signf(a.x) * sa.x); o[1] = (bf16_t)(signf(a.y) * sa.y);
    o[2] = (bf16_t)(signf(a.z) * sa.z); o[3] = (bf16_t)(signf(a.w) * sa.w);
    o[4] = (bf16_t)(signf(b.x) * sb.x); o[5] = (bf16_t)(signf(b.y) * sb.y);
    o[6] = (bf16_t)(signf(b.z) * sb.z); o[7] = (bf16_t)(signf(b.w) * sb.w);
    reinterpret_cast<bf16x8*>(out)[idx] = o;
}

__global__ void build_wcat_kernel(const float* __restrict__ U, const float* __restrict__ v1,
                                  const float* __restrict__ u2, const float* __restrict__ u1,
                                  const float* __restrict__ U_R, const float* __restrict__ v1_R,
                                  const float* __restrict__ u2_R, const float* __restrict__ u1_R,
                                  bf16_t* __restrict__ out) {
    int idx = blockIdx.x * blockDim.x + threadIdx.x;
    int j  = idx >> 8;
    int s0 = (idx & 255) * 8;
    const float* srcU; const float* sv1; const float* su2; float amp;
    if (s0 < DIM_S) { srcU = U   + (size_t)j * DIM_S + s0; sv1 = v1 + s0;   su2 = u2 + s0;   amp = u1[j];   }
    else { int s = s0 - DIM_S;
           srcU = U_R + (size_t)j * DIM_S + s;  sv1 = v1_R + s; su2 = u2_R + s; amp = u1_R[j]; }
    float4 a  = *reinterpret_cast<const float4*>(srcU);
    float4 b  = *reinterpret_cast<const float4*>(srcU + 4);
    float4 va = *reinterpret_cast<const float4*>(sv1);
    float4 vb = *reinterpret_cast<const float4*>(sv1 + 4);
    float4 ua = *reinterpret_cast<const float4*>(su2);
    float4 ub = *reinterpret_cast<const float4*>(su2 + 4);
    bf16x8 o;
    o[0] = (bf16_t)(amp * va.x * ua.x * signf(a.x));
    o[1] = (bf16_t)(amp * va.y * ua.y * signf(a.y));
    o[2] = (bf16_t)(amp * va.z * ua.z * signf(a.z));
    o[3] = (bf16_t)(amp * va.w * ua.w * signf(a.w));
    o[4] = (bf16_t)(amp * vb.x * ub.x * signf(b.x));
    o[5] = (bf16_t)(amp * vb.y * ub.y * signf(b.y));
    o[6] = (bf16_t)(amp * vb.z * ub.z * signf(b.z));
    o[7] = (bf16_t)(amp * vb.w * ub.w * signf(b.w));
    reinterpret_cast<bf16x8*>(out)[idx] = o;
}

// ---------------- 256x256 loose-sync GEMM, 32x32x16 MFMA ----------------
// C[M][N] = A[M][K] @ B[N][K]^T. 512 thr = 8 waves (2Mx4N), per-wave 128x64
// as 4m x 2n tiles of 32x32. BK=64. LDS 128 KiB, sub-tile [128 rows][64 cols]
// (16 KB), A: buf*32768 + mh*16384; B at +65536 with nh.
// Swizzle: LDS[off] = G[off ^ (((off>>7)&7)<<4)] via pre-swizzled stage source;
// reads use slot = ((kk*2|hi) ^ (lane&7))<<4 (exact inverse, row-keyed).
// Sync: ONE vmcnt(0)+barrier per K-tile; k-step frag reads ping-pong one step
// ahead; last MFMA cluster deferred past the barrier to overlap next-tile reads.

#define VMCNT0() do { asm volatile("s_waitcnt vmcnt(0)" ::: "memory"); \
                      __builtin_amdgcn_sched_barrier(0); } while (0)

template<int N, int K, bool OUT_BF16>
__global__ __launch_bounds__(512, 2) void gemm256_kernel(
        const bf16_t* __restrict__ A, const bf16_t* __restrict__ B,
        bf16_t* __restrict__ Cb, float* __restrict__ Cf,
        const float* __restrict__ bias) {
    extern __shared__ char lds[];
    constexpr int NT = K / 64;
    static_assert(NT >= 2, "K too small");
    const int tid  = threadIdx.x;
    const int wave = tid >> 6;
    const int lane = tid & 63;
    const int wr = wave >> 2;    // 0..1  (M-half)
    const int wc = wave & 3;     // 0..3  (64-col N slice)

    // T1: XCD-aware bijective swizzle (nwg % 8 == 0 for both GEMMs)
    const int nwg  = gridDim.x;
    const int orig = blockIdx.x;
    const int swz  = (orig & 7) * (nwg >> 3) + (orig >> 3);
    constexpr int NTX = N / 256;
    const int n0 = (swz % NTX) * 256;
    const int m0 = (swz / NTX) * 256;

    char* ldsA = lds;
    char* ldsB = lds + 65536;

    // ---- staging source pointers (pre-inverse-swizzled; LDS dest linear) ----
    const char* gA[2]; const char* gB[2];
#pragma unroll
    for (int j = 0; j < 2; ++j) {
        int off = j * 8192 + wave * 1024 + lane * 16;
        int lg  = off ^ (((off >> 7) & 7) << 4);
        int row = lg >> 7;          // 0..127
        int cb  = lg & 127;         // byte within 128B row
        gA[j] = (const char*)A + (size_t)(m0 + row) * (K * 2) + cb;
        gB[j] = (const char*)B + (size_t)(n0 + row) * (K * 2) + cb;
    }

#define STAGE_A(t_, mh) do { \
    int _lo = (((t_) & 1) << 15) + ((mh) << 14) + (wave << 10); \
    size_t _ga = (size_t)(mh) * (128 * K * 2) + (size_t)(t_) * 128; \
    __builtin_amdgcn_global_load_lds((gvoid_t*)(gA[0] + _ga), (lvoid_t*)(ldsA + _lo), 16, 0, 0); \
    __builtin_amdgcn_global_load_lds((gvoid_t*)(gA[1] + _ga), (lvoid_t*)(ldsA + _lo + 8192), 16, 0, 0); \
} while (0)
#define STAGE_B(t_, nh) do { \
    int _lo = (((t_) & 1) << 15) + ((nh) << 14) + (wave << 10); \
    size_t _ga = (size_t)(nh) * (128 * K * 2) + (size_t)(t_) * 128; \
    __builtin_amdgcn_global_load_lds((gvoid_t*)(gB[0] + _ga), (lvoid_t*)(ldsB + _lo), 16, 0, 0); \
    __builtin_amdgcn_global_load_lds((gvoid_t*)(gB[1] + _ga), (lvoid_t*)(ldsB + _lo + 8192), 16, 0, 0); \
} while (0)

    // ---- read offsets: per-kk swizzled bases; m/n-tile step is +4096 imm ----
    const int hi = lane >> 5;       // k-slice within 32B window
    const int lk = lane & 7;        // swizzle key
    int oA[4], oB[4];
#pragma unroll
    for (int kk = 0; kk < 4; ++kk) {
        int slot = (((kk << 1) | hi) ^ lk) << 4;
        oA[kk] = (wr << 14) + (lane & 31) * 128 + slot;
        oB[kk] = 65536 + ((wc >> 1) << 14) + ((wc & 1) << 13) + (lane & 31) * 128 + slot;
    }

#define RD_A(dst, kk) do { \
    _Pragma("unroll") \
    for (int mi = 0; mi < 4; ++mi) \
        dst[mi] = *(const bf16x8*)(lds + oA[kk] + mi * 4096); \
} while (0)
#define RD_B(dst, kk) do { \
    _Pragma("unroll") \
    for (int ni = 0; ni < 2; ++ni) \
        dst[ni] = *(const bf16x8*)(lds + oB[kk] + ni * 4096); \
} while (0)
#define FLIP() do { \
    _Pragma("unroll") \
    for (int kk = 0; kk < 4; ++kk) { oA[kk] ^= 0x8000; oB[kk] ^= 0x8000; } \
} while (0)
#define MFMA8(AF, BF) do { \
    __builtin_amdgcn_s_setprio(1); \
    _Pragma("unroll") \
    for (int mi = 0; mi < 4; ++mi) \
        _Pragma("unroll") \
        for (int ni = 0; ni < 2; ++ni) \
            acc[mi][ni] = __builtin_amdgcn_mfma_f32_32x32x16_bf16( \
                AF[mi], BF[ni], acc[mi][ni], 0, 0, 0); \
    __builtin_amdgcn_s_setprio(0); \
} while (0)

    f32x16 acc[4][2];
#pragma unroll
    for (int m = 0; m < 4; ++m)
#pragma unroll
        for (int n = 0; n < 2; ++n)
#pragma unroll
            for (int j = 0; j < 16; ++j)
                acc[m][n][j] = 0.f;

    bf16x8 afP[4], afQ[4], bfP[2], bfQ[2];

    // prologue: stage all 4 sub-tiles of t=0, publish, read kk0 frags
    STAGE_A(0, 0); STAGE_A(0, 1);
    STAGE_B(0, 0); STAGE_B(0, 1);
    VMCNT0();
    __builtin_amdgcn_s_barrier();
    RD_A(afP, 0); RD_B(bfP, 0);

    for (int t = 0; t < NT; ++t) {
        const bool i1 = (t + 1 < NT);
        // kk0: prefetch kk1 frags; issue next-tile A staging
        if (i1) { STAGE_A(t + 1, 0); STAGE_A(t + 1, 1); }
        RD_A(afQ, 1); RD_B(bfQ, 1);
        MFMA8(afP, bfP);
        // kk1: prefetch kk2; issue next-tile B staging
        if (i1) { STAGE_B(t + 1, 0); STAGE_B(t + 1, 1); }
        RD_A(afP, 2); RD_B(bfP, 2);
        MFMA8(afQ, bfQ);
        // kk2: prefetch kk3
        RD_A(afQ, 3); RD_B(bfQ, 3);
        MFMA8(afP, bfP);
        // kk3: publish next tile, then overlap its kk0 reads with kk3 MFMA
        if (i1) { VMCNT0(); }
        __builtin_amdgcn_s_barrier();
        if (i1) { FLIP(); RD_A(afP, 0); RD_B(bfP, 0); }
        MFMA8(afQ, bfQ);
    }

#undef RD_A
#undef RD_B
#undef FLIP
#undef MFMA8
#undef STAGE_A
#undef STAGE_B

    // epilogue: 32x32 C/D layout (m74/m101): col=lane&31,
    // row = (reg&3) + 8*(reg>>2) + 4*(lane>>5)
    const int cc = lane & 31;
    const int rhi = (lane >> 5) * 4;
#pragma unroll
    for (int m = 0; m < 4; ++m) {
#pragma unroll
        for (int n = 0; n < 2; ++n) {
            const int col = n0 + wc * 64 + n * 32 + cc;
            const float bv = OUT_BF16 ? 0.f : bias[col];
#pragma unroll
            for (int j = 0; j < 16; ++j) {
                const int row = m0 + wr * 128 + m * 32 + (j & 3) + 8 * (j >> 2) + rhi;
                if (OUT_BF16)
                    Cb[(size_t)row * N + col] = (bf16_t)acc[m][n][j];
                else
                    Cf[(size_t)row * N + col] = acc[m][n][j] + bv;
            }
        }
    }
}

// ---------------- launch ----------------
extern "C" void kernel_launch(void* const* d_in, const int* in_sizes, int n_in,
                              void* d_out, int out_size, void* d_ws, size_t ws_size,
                              hipStream_t stream) {
    const float* x    = (const float*)d_in[0];
    const float* V    = (const float*)d_in[1];
    const float* U    = (const float*)d_in[2];
    const float* v2   = (const float*)d_in[3];
    const float* v1   = (const float*)d_in[4];
    const float* u2   = (const float*)d_in[5];
    const float* u1   = (const float*)d_in[6];
    const float* V_R  = (const float*)d_in[7];
    const float* U_R  = (const float*)d_in[8];
    const float* v2_R = (const float*)d_in[9];
    const float* v1_R = (const float*)d_in[10];
    const float* u2_R = (const float*)d_in[11];
    const float* u1_R = (const float*)d_in[12];
    const float* bias = (const float*)d_in[13];
    float* out = (float*)d_out;

    char* ws = (char*)d_ws;
    bf16_t* Xb   = (bf16_t*)(ws);                                  // 64 MB: [8192][4096]
    bf16_t* Vcat = (bf16_t*)(ws + (size_t)64  * 1024 * 1024);      // 16 MB: [2048][4096]
    bf16_t* Wcat = (bf16_t*)(ws + (size_t)80  * 1024 * 1024);      // 16 MB: [4096][2048]
    bf16_t* Hb   = (bf16_t*)(ws + (size_t)96  * 1024 * 1024);      // 32 MB: [8192][2048]

    (void)hipFuncSetAttribute((const void*)gemm256_kernel<DIM_S2, DIM_IN, true>,
                              hipFuncAttributeMaxDynamicSharedMemorySize, 131072);
    (void)hipFuncSetAttribute((const void*)gemm256_kernel<DIM_OUT, DIM_S2, false>,
                              hipFuncAttributeMaxDynamicSharedMemorySize, 131072);

    cast_x_kernel    <<<16384, 256, 0, stream>>>(x, Xb);
    build_vcat_kernel<<<4096, 256, 0, stream>>>(V, v2, V_R, v2_R, Vcat);
    build_wcat_kernel<<<4096, 256, 0, stream>>>(U, v1, u2, u1, U_R, v1_R, u2_R, u1_R, Wcat);

    // GEMM1: H[8192][2048] = Xb @ Vcat^T   (K=4096), grid 8x32=256
    gemm256_kernel<DIM_S2, DIM_IN, true>
        <<<(DIM_S2 / 256) * (NROWS / 256), 512, 131072, stream>>>(Xb, Vcat, Hb, nullptr, nullptr);
    // GEMM2: out[8192][4096] = Hb @ Wcat^T + bias   (K=2048), grid 16x32=512
    gemm256_kernel<DIM_OUT, DIM_S2, false>
        <<<(DIM_OUT / 256) * (NROWS / 256), 512, 131072, stream>>>(Hb, Wcat, nullptr, out, bias);
}